// Round 8
// baseline (441.932 us; speedup 1.0000x reference)
//
#include <hip/hip_runtime.h>

typedef _Float16 f16;
typedef _Float16 f16x4 __attribute__((ext_vector_type(4)));
typedef _Float16 f16x8 __attribute__((ext_vector_type(8)));
typedef float    f32x4 __attribute__((ext_vector_type(4)));
typedef float    f32x16 __attribute__((ext_vector_type(16)));
typedef unsigned int u32;

#define MFMA_F16(a,b,c)  __builtin_amdgcn_mfma_f32_16x16x32_f16((a),(b),(c),0,0,0)
#define MFMA32(a,b,c)    __builtin_amdgcn_mfma_f32_32x32x16_f16((a),(b),(c),0,0,0)

__device__ __forceinline__ u32 pkf16(float a, float b) {
  return __builtin_bit_cast(u32, __builtin_amdgcn_cvt_pkrtz(a, b));
}
union F8U4 { u32 d[4]; f16x8 v; };

__device__ __forceinline__ f16x8 comb(f16x4 a, f16x4 b) {
  f16x8 r;
  #pragma unroll
  for (int i = 0; i < 4; ++i) { r[i] = a[i]; r[4 + i] = b[i]; }
  return r;
}

// ---------------- FFT-layout matrices (exact 0/+-1 entries) ----------------
__device__ __forceinline__ float T_val(int rr, int cc) {
  int p = rr >> 2, f = rr & 3;
  int c = cc >> 2, d = (cc >> 1) & 1, e = cc & 1;
  int q = f & 1;
  int m = (p * c + 2 * q * d) & 3;
  float cs = (m == 0) ? 1.f : (m == 2) ? -1.f : 0.f;
  float sn = (m == 1) ? 1.f : (m == 3) ? -1.f : 0.f;
  if (f < 2) return (e == 0) ? cs : sn;
  return (e == 0) ? -sn : cs;
}
__device__ __forceinline__ float U_val(int rr, int cc) {
  int p = rr >> 2, f = rr & 3;
  int c = cc >> 2, d = (cc >> 1) & 1, e = cc & 1;
  int q = f & 1;
  int m = (p * c + 2 * q * d) & 3;
  float cs = (m == 0) ? 1.f : (m == 2) ? -1.f : 0.f;
  float sn = (m == 1) ? 1.f : (m == 3) ? -1.f : 0.f;
  float v;
  if (f < 2) v = (e == 0) ? cs : -sn;
  else       v = (e == 0) ? sn : cs;
  return v * 0.125f;
}

// ---------------- P1: Wq_eff / Wk_eff (fp32) ----------------
__global__ void prep_qk(const float* __restrict__ Wq, const float* __restrict__ Wk,
                        float* __restrict__ WqE, float* __restrict__ WkE) {
  int b = blockIdx.x;
  int isK = b >> 11;
  int h = (b >> 8) & 7;
  int dd = b & 255;
  const float* W = isK ? Wk : Wq;
  float* E = isK ? WkE : WqE;
  int k = threadIdx.x;
  size_t base = (size_t)h * 65536;
  float v;
  if (h < 3) {
    v = W[base + (size_t)dd * 256 + k];
  } else {
    int g = dd >> 4, i = dd & 15;
    float s = 0.f;
    for (int ip = 0; ip < 16; ++ip) {
      float t = T_val(ip, i);
      if (t != 0.f) s += t * W[base + (size_t)(g * 16 + ip) * 256 + k];
    }
    v = s;
  }
  E[base + (size_t)dd * 256 + k] = v;
}

// ---------------- P2: Mt[h][d'][d] = (Wq_eff . Wk_eff^T)[d][d'] / 16 (fp16)
__global__ void prep_m(const float* __restrict__ WqE, const float* __restrict__ WkE,
                       f16* __restrict__ Mt) {
  __shared__ float Aq[32][33];
  __shared__ float Bk[32][33];
  int h = blockIdx.x >> 6;
  int dpt = (blockIdx.x >> 3) & 7;
  int dt = blockIdx.x & 7;
  int tid = threadIdx.x;
  int drow = tid & 31;
  int dprow4 = (tid >> 5) * 4;
  float acc0 = 0.f, acc1 = 0.f, acc2 = 0.f, acc3 = 0.f;
  int r = tid >> 3;
  int c0 = (tid & 7) * 4;
  for (int kt = 0; kt < 8; ++kt) {
    for (int jj = 0; jj < 4; ++jj) {
      Aq[r][c0 + jj] = WqE[(size_t)h * 65536 + (size_t)(dt * 32 + r) * 256 + kt * 32 + c0 + jj];
      Bk[r][c0 + jj] = WkE[(size_t)h * 65536 + (size_t)(dpt * 32 + r) * 256 + kt * 32 + c0 + jj];
    }
    __syncthreads();
    #pragma unroll
    for (int k = 0; k < 32; ++k) {
      float a = Aq[drow][k];
      acc0 += a * Bk[dprow4 + 0][k];
      acc1 += a * Bk[dprow4 + 1][k];
      acc2 += a * Bk[dprow4 + 2][k];
      acc3 += a * Bk[dprow4 + 3][k];
    }
    __syncthreads();
  }
  int d_ = dt * 32 + drow;
  size_t ob = (size_t)h * 65536 + (size_t)(dpt * 32 + dprow4) * 256 + d_;
  Mt[ob + 0 * 256] = (f16)(acc0 * 0.0625f);
  Mt[ob + 1 * 256] = (f16)(acc1 * 0.0625f);
  Mt[ob + 2 * 256] = (f16)(acc2 * 0.0625f);
  Mt[ob + 3 * 256] = (f16)(acc3 * 0.0625f);
}

// ---------------- P3: Wvt[h][k'][d] = Wv_eff[d][k'] / NUM_HEADS (fp16)
__global__ void prep_v(const float* __restrict__ Wv, f16* __restrict__ Wvt) {
  __shared__ float Ts[16][16];
  __shared__ float Us[16][16];
  int h = blockIdx.x >> 8;
  int kp = blockIdx.x & 255;
  int tid = threadIdx.x;
  Ts[tid >> 4][tid & 15] = T_val(tid >> 4, tid & 15);
  Us[tid >> 4][tid & 15] = U_val(tid >> 4, tid & 15);
  __syncthreads();
  int d = tid;
  int g = d >> 4, i = d & 15;
  int gp = kp >> 4, fp = kp & 15;
  float s = 0.f;
  if (h < 3) {
    s = Wv[(size_t)h * 65536 + (size_t)d * 256 + kp];
  } else {
    for (int ip = 0; ip < 16; ++ip) {
      float tv = Ts[ip][i];
      if (tv != 0.f) {
        float inner = 0.f;
        for (int jj = 0; jj < 16; ++jj) {
          float uv = Us[fp][jj];
          if (uv != 0.f)
            inner += uv * Wv[(size_t)h * 65536 + (size_t)(g * 16 + ip) * 256 + gp * 16 + jj];
        }
        s += tv * inner;
      }
    }
  }
  Wvt[(size_t)h * 65536 + (size_t)kp * 256 + d] = (f16)(s * 0.125f);
}

// ---------------- P4a: repack Wv to 16x16x32 fragment-major ----------------
// WvF[h][t16][kt][lane][8] = Wvt[h][t16*16 + (l&15)][kt*32 + (l>>4)*8 + j]
__global__ void repackV(const f16* __restrict__ Wvt, f16* __restrict__ WvF) {
  int bid = blockIdx.x;              // 1024 = 8h * 16t * 8kt
  int h = (bid >> 7) & 7;
  int t16 = (bid >> 3) & 15;
  int kt = bid & 7;
  int l = threadIdx.x;               // 64
  size_t sb = (size_t)h * 65536 + (size_t)(t16 * 16 + (l & 15)) * 256 + kt * 32 + (l >> 4) * 8;
  size_t db = ((size_t)((h * 16 + t16) * 8 + kt) * 64 + l) * 8;
  *(f16x8*)(WvF + db) = *(const f16x8*)(Wvt + sb);
}

// ---------------- P4b: repack Mt to 32x32x16 fragment-major ----------------
// MtF32[h][dpt][kt][lane][8] = Mt[h][dpt*32 + (l&31)][kt*16 + (l>>5)*8 + j]
__global__ void repackM32(const f16* __restrict__ Mt, f16* __restrict__ MtF32) {
  int bid = blockIdx.x;              // 1024 = 8h * 8dpt * 16kt
  int h = (bid >> 7) & 7;
  int dpt = (bid >> 4) & 7;
  int kt = bid & 15;
  int l = threadIdx.x;               // 64
  size_t sb = (size_t)h * 65536 + (size_t)(dpt * 32 + (l & 31)) * 256 + kt * 16 + (l >> 5) * 8;
  size_t db = ((size_t)((h * 8 + dpt) * 16 + kt) * 64 + l) * 8;
  *(f16x8*)(MtF32 + db) = *(const f16x8*)(Mt + sb);
}

// ---------------- Main fused kernel ----------------
// 512 thr (8 waves), 2 batches/block, grid 2048, LDS 70144 B -> 2 blocks/CU:
//   Xs [64 rows][256] f16, swz col ^ ((row&7)<<3)   32768 B
//   Y  [64 s][256 d'] f16, same swz                 32768 B
//   Aat [2b][32 s][36] f16 (stride 36 = 18 banks)    4608 B
// Wave roles:
//   P1a Y (32x32x16): wave w = d'-tile of 32, covers both batches (2 s-tiles)
//   P1b V (16x16x32): wave w = k'-slice of 32, covers all 4 row-tiles -> regs
//   P2 (waves 0-3 only): (bq = w>>1, mt = w&1), full 4-r parity softmax
//   P3/store: wave w = k'-slice, both batches, PV in registers
__global__ __launch_bounds__(512, 4) void mha_main(
    const float* __restrict__ xg_all,
    const f16* __restrict__ MtF32,
    const f16* __restrict__ WvF,
    float* __restrict__ outG)
{
  extern __shared__ char smem[];
  f16* Xs  = (f16*)smem;
  f16* Y   = (f16*)(smem + 32768);
  f16* Aat = (f16*)(smem + 65536);

  const int tid = threadIdx.x;
  const int w   = tid >> 6;
  const int l   = tid & 63;
  const int l15 = l & 15;
  const int l4  = l >> 4;
  const int l31 = l & 31;
  const int hi  = l >> 5;

  // ---- stage x (2 batches, fp32 -> fp16, swizzled) ----
  const float* xg = xg_all + (size_t)blockIdx.x * 16384;
  #pragma unroll 4
  for (int i = 0; i < 8; ++i) {
    int f4 = i * 512 + tid;
    int row = f4 >> 6;
    int col = (f4 & 63) << 2;
    f32x4 v = *(const f32x4*)(xg + (size_t)f4 * 4);
    f16x4 hv;
    hv[0] = (f16)v[0]; hv[1] = (f16)v[1]; hv[2] = (f16)v[2]; hv[3] = (f16)v[3];
    *(f16x4*)(Xs + row * 256 + (col ^ ((row & 7) << 3))) = hv;
  }
  __syncthreads();

  const int bq = w >> 1, mt = w & 1;   // P2 split (waves 0-3)

  // persistent O accumulators: [batch][s-tile][k'-tile] for wave's k'-slice w
  f32x4 O[2][2][2];
  #pragma unroll
  for (int b = 0; b < 2; ++b)
    #pragma unroll
    for (int sm = 0; sm < 2; ++sm)
      #pragma unroll
      for (int n = 0; n < 2; ++n)
        O[b][sm][n] = (f32x4){0.f, 0.f, 0.f, 0.f};

  for (int h = 0; h < 8; ++h) {
    // ========== P1a: Y = Mt . x^T (32x32x16; wave = d'-tile w) ==========
    {
      f32x16 C0, C1;
      #pragma unroll
      for (int i = 0; i < 16; ++i) { C0[i] = 0.f; C1[i] = 0.f; }
      const f16* Abase = MtF32 + ((size_t)((h * 8 + w) * 16) * 64 + l) * 8;
      #pragma unroll 4
      for (int kt = 0; kt < 16; ++kt) {
        f16x8 A = *(const f16x8*)(Abase + kt * 512);
        int cb = kt * 16 + hi * 8;
        f16x8 B0 = *(const f16x8*)(Xs + l31 * 256 + (cb ^ ((l31 & 7) << 3)));
        int r1 = 32 + l31;
        f16x8 B1 = *(const f16x8*)(Xs + r1 * 256 + (cb ^ ((r1 & 7) << 3)));
        __builtin_amdgcn_s_setprio(1);
        C0 = MFMA32(A, B0, C0);
        C1 = MFMA32(A, B1, C1);
        __builtin_amdgcn_s_setprio(0);
      }
      // write Y: C col = lane&31 = s, row = (r&3) + 8*(r>>2) + 4*hi = d' (in-tile)
      #pragma unroll
      for (int q = 0; q < 4; ++q) {
        int dcol = w * 32 + q * 8 + hi * 4;
        f16x4 h0, h1;
        #pragma unroll
        for (int j = 0; j < 4; ++j) { h0[j] = (f16)C0[q * 4 + j]; h1[j] = (f16)C1[q * 4 + j]; }
        int s0 = l31, s1 = 32 + l31;
        *(f16x4*)(Y + s0 * 256 + (dcol ^ ((s0 & 7) << 3))) = h0;
        *(f16x4*)(Y + s1 * 256 + (dcol ^ ((s1 & 7) << 3))) = h1;
      }
    }
    // ========== P1b: V = x . Wv (16x16x32; k'-slice w, all rows) -> regs ======
    u32 Vh[4][2][2];
    {
      f32x4 VC[4][2];
      #pragma unroll
      for (int tau = 0; tau < 4; ++tau)
        #pragma unroll
        for (int n = 0; n < 2; ++n) VC[tau][n] = (f32x4){0.f, 0.f, 0.f, 0.f};
      #pragma unroll 2
      for (int kt = 0; kt < 8; ++kt) {
        f16x8 Bw[2], Ax[4];
        #pragma unroll
        for (int n = 0; n < 2; ++n)
          Bw[n] = *(const f16x8*)(WvF + ((size_t)((h * 16 + w * 2 + n) * 8 + kt) * 64 + l) * 8);
        #pragma unroll
        for (int tau = 0; tau < 4; ++tau) {
          int xrow = tau * 16 + l15;
          Ax[tau] = *(const f16x8*)(Xs + xrow * 256 + ((kt * 32 + l4 * 8) ^ ((xrow & 7) << 3)));
        }
        __builtin_amdgcn_s_setprio(1);
        #pragma unroll
        for (int tau = 0; tau < 4; ++tau)
          #pragma unroll
          for (int n = 0; n < 2; ++n)
            VC[tau][n] = MFMA_F16(Ax[tau], Bw[n], VC[tau][n]);
        __builtin_amdgcn_s_setprio(0);
      }
      #pragma unroll
      for (int tau = 0; tau < 4; ++tau)
        #pragma unroll
        for (int n = 0; n < 2; ++n) {
          Vh[tau][n][0] = pkf16(VC[tau][n][0], VC[tau][n][1]);
          Vh[tau][n][1] = pkf16(VC[tau][n][2], VC[tau][n][3]);
        }
    }
    __syncthreads();   // BAR1: Y visible

    // ========== P2 (waves 0-3): scores + parity softmax ==========
    if (w < 4) {
      f32x4 S0 = (f32x4){0.f, 0.f, 0.f, 0.f};
      f32x4 S1 = (f32x4){0.f, 0.f, 0.f, 0.f};
      int yrow = bq * 32 + mt * 16 + l15;
      int x0 = bq * 32 + l15;
      int x1 = bq * 32 + 16 + l15;
      #pragma unroll
      for (int kt = 0; kt < 8; ++kt) {
        int ks = kt * 32 + l4 * 8;
        f16x8 ay = *(const f16x8*)(Y + yrow * 256 + (ks ^ ((yrow & 7) << 3)));
        f16x8 b0 = *(const f16x8*)(Xs + x0 * 256 + (ks ^ ((x0 & 7) << 3)));
        f16x8 b1 = *(const f16x8*)(Xs + x1 * 256 + (ks ^ ((x1 & 7) << 3)));
        S0 = MFMA_F16(ay, b0, S0);
        S1 = MFMA_F16(ay, b1, S1);
      }
      #pragma unroll
      for (int r = 0; r < 4; ++r) {
        bool valid = ((l & 1) == (r & 1));      // t parity == s parity
        float v0 = valid ? S0[r] : -1e30f;
        float v1 = valid ? S1[r] : -1e30f;
        float mx = fmaxf(v0, v1);
        mx = fmaxf(mx, __shfl_xor(mx, 1));
        mx = fmaxf(mx, __shfl_xor(mx, 2));
        mx = fmaxf(mx, __shfl_xor(mx, 4));
        mx = fmaxf(mx, __shfl_xor(mx, 8));
        float e0 = valid ? __expf(v0 - mx) : 0.f;
        float e1 = valid ? __expf(v1 - mx) : 0.f;
        float sm = e0 + e1;
        sm += __shfl_xor(sm, 1);
        sm += __shfl_xor(sm, 2);
        sm += __shfl_xor(sm, 4);
        sm += __shfl_xor(sm, 8);
        float inv = 1.f / sm;
        int s = mt * 16 + l4 * 4 + r;
        Aat[(bq * 32 + s) * 36 + l15] = (f16)(e0 * inv);
        Aat[(bq * 32 + s) * 36 + 16 + l15] = (f16)(e1 * inv);
      }
    }
    __syncthreads();   // BAR2: Aat visible, all Y reads done

    // ========== P3: O += A . V (all in registers) ==========
    #pragma unroll
    for (int b = 0; b < 2; ++b) {
      #pragma unroll
      for (int sm = 0; sm < 2; ++sm) {
        int arow = (b * 32 + sm * 16 + l15) * 36 + l4 * 4;
        f16x8 bf = comb(*(const f16x4*)(Aat + arow),
                        *(const f16x4*)(Aat + arow + 16));
        #pragma unroll
        for (int n = 0; n < 2; ++n) {
          F8U4 av;
          av.d[0] = Vh[b * 2 + 0][n][0];
          av.d[1] = Vh[b * 2 + 0][n][1];
          av.d[2] = Vh[b * 2 + 1][n][0];
          av.d[3] = Vh[b * 2 + 1][n][1];
          O[b][sm][n] = MFMA_F16(av.v, bf, O[b][sm][n]);
        }
      }
    }
    // no barrier: next P1a writes Y only after this head's BAR2; Aat(h+1)
    // written only after next BAR1.
  }

  // ---- store O: out[b][s][k'], lane=s, regs=k' quad ----
  #pragma unroll
  for (int b = 0; b < 2; ++b) {
    float* ob = outG + ((size_t)blockIdx.x * 2 + b) * 8192;
    #pragma unroll
    for (int sm = 0; sm < 2; ++sm) {
      int s = sm * 16 + l15;
      #pragma unroll
      for (int n = 0; n < 2; ++n) {
        int kp = w * 32 + n * 16 + l4 * 4;
        *(f32x4*)(ob + s * 256 + kp) = O[b][sm][n];
      }
    }
  }
}

// ---------------- launch ----------------
extern "C" void kernel_launch(void* const* d_in, const int* in_sizes, int n_in,
                              void* d_out, int out_size, void* d_ws, size_t ws_size,
                              hipStream_t stream) {
  const float* x  = (const float*)d_in[0];
  const float* Wq = (const float*)d_in[1];
  const float* Wk = (const float*)d_in[2];
  const float* Wv = (const float*)d_in[3];
  float* out = (float*)d_out;
  char* ws = (char*)d_ws;
  float* WqE = (float*)ws;                       // 2 MB (dead after prep_m)
  float* WkE = (float*)(ws + 2097152);           // 2 MB (dead after prep_m)
  f16*   Mt  = (f16*)(ws + 4194304);             // 1 MB fp16
  f16*   Wvt = (f16*)(ws + 5242880);             // 1 MB fp16
  f16*   MtF32 = (f16*)ws;                       // 1 MB, overlays WqE
  f16*   WvF   = (f16*)(ws + 2097152);           // 1 MB, overlays WkE

  prep_qk<<<4096, 256, 0, stream>>>(Wq, Wk, WqE, WkE);
  prep_m<<<512, 256, 0, stream>>>(WqE, WkE, Mt);
  prep_v<<<2048, 256, 0, stream>>>(Wv, Wvt);
  repackM32<<<1024, 64, 0, stream>>>(Mt, MtF32);
  repackV<<<1024, 64, 0, stream>>>(Wvt, WvF);
  mha_main<<<2048, 512, 70144, stream>>>(x, MtF32, WvF, out);
}

// Round 9
// 399.935 us; speedup vs baseline: 1.1050x; 1.1050x over previous
//
#include <hip/hip_runtime.h>

typedef _Float16 f16;
typedef _Float16 f16x4 __attribute__((ext_vector_type(4)));
typedef _Float16 f16x8 __attribute__((ext_vector_type(8)));
typedef float    f32x4 __attribute__((ext_vector_type(4)));
typedef unsigned int u32;

#define MFMA_F16(a,b,c) __builtin_amdgcn_mfma_f32_16x16x32_f16((a),(b),(c),0,0,0)

// LDS row stride for Xs/Y: 264 f16 = 132 dwords === 4 (mod 32) -> each row
// shifts one bank-quad; rows stay 16B-aligned. No XOR swizzle needed (all
// accesses are row-wise b128/b64; no column reads exist in this kernel).
#define XST 264

__device__ __forceinline__ u32 pkf16(float a, float b) {
  return __builtin_bit_cast(u32, __builtin_amdgcn_cvt_pkrtz(a, b));
}
union F8U4 { u32 d[4]; f16x8 v; };

__device__ __forceinline__ f16x8 comb(f16x4 a, f16x4 b) {
  f16x8 r;
  #pragma unroll
  for (int i = 0; i < 4; ++i) { r[i] = a[i]; r[4 + i] = b[i]; }
  return r;
}

// ---------------- FFT-layout matrices (exact 0/+-1 entries) ----------------
__device__ __forceinline__ float T_val(int rr, int cc) {
  int p = rr >> 2, f = rr & 3;
  int c = cc >> 2, d = (cc >> 1) & 1, e = cc & 1;
  int q = f & 1;
  int m = (p * c + 2 * q * d) & 3;
  float cs = (m == 0) ? 1.f : (m == 2) ? -1.f : 0.f;
  float sn = (m == 1) ? 1.f : (m == 3) ? -1.f : 0.f;
  if (f < 2) return (e == 0) ? cs : sn;
  return (e == 0) ? -sn : cs;
}
__device__ __forceinline__ float U_val(int rr, int cc) {
  int p = rr >> 2, f = rr & 3;
  int c = cc >> 2, d = (cc >> 1) & 1, e = cc & 1;
  int q = f & 1;
  int m = (p * c + 2 * q * d) & 3;
  float cs = (m == 0) ? 1.f : (m == 2) ? -1.f : 0.f;
  float sn = (m == 1) ? 1.f : (m == 3) ? -1.f : 0.f;
  float v;
  if (f < 2) v = (e == 0) ? cs : -sn;
  else       v = (e == 0) ? sn : cs;
  return v * 0.125f;
}

// ---------------- P1: Wq_eff / Wk_eff (fp32) ----------------
__global__ void prep_qk(const float* __restrict__ Wq, const float* __restrict__ Wk,
                        float* __restrict__ WqE, float* __restrict__ WkE) {
  int b = blockIdx.x;
  int isK = b >> 11;
  int h = (b >> 8) & 7;
  int dd = b & 255;
  const float* W = isK ? Wk : Wq;
  float* E = isK ? WkE : WqE;
  int k = threadIdx.x;
  size_t base = (size_t)h * 65536;
  float v;
  if (h < 3) {
    v = W[base + (size_t)dd * 256 + k];
  } else {
    int g = dd >> 4, i = dd & 15;
    float s = 0.f;
    for (int ip = 0; ip < 16; ++ip) {
      float t = T_val(ip, i);
      if (t != 0.f) s += t * W[base + (size_t)(g * 16 + ip) * 256 + k];
    }
    v = s;
  }
  E[base + (size_t)dd * 256 + k] = v;
}

// ---------------- P2: Mt[h][d'][d] = (Wq_eff . Wk_eff^T)[d][d'] / 16 (fp16)
__global__ void prep_m(const float* __restrict__ WqE, const float* __restrict__ WkE,
                       f16* __restrict__ Mt) {
  __shared__ float Aq[32][33];
  __shared__ float Bk[32][33];
  int h = blockIdx.x >> 6;
  int dpt = (blockIdx.x >> 3) & 7;
  int dt = blockIdx.x & 7;
  int tid = threadIdx.x;
  int drow = tid & 31;
  int dprow4 = (tid >> 5) * 4;
  float acc0 = 0.f, acc1 = 0.f, acc2 = 0.f, acc3 = 0.f;
  int r = tid >> 3;
  int c0 = (tid & 7) * 4;
  for (int kt = 0; kt < 8; ++kt) {
    for (int jj = 0; jj < 4; ++jj) {
      Aq[r][c0 + jj] = WqE[(size_t)h * 65536 + (size_t)(dt * 32 + r) * 256 + kt * 32 + c0 + jj];
      Bk[r][c0 + jj] = WkE[(size_t)h * 65536 + (size_t)(dpt * 32 + r) * 256 + kt * 32 + c0 + jj];
    }
    __syncthreads();
    #pragma unroll
    for (int k = 0; k < 32; ++k) {
      float a = Aq[drow][k];
      acc0 += a * Bk[dprow4 + 0][k];
      acc1 += a * Bk[dprow4 + 1][k];
      acc2 += a * Bk[dprow4 + 2][k];
      acc3 += a * Bk[dprow4 + 3][k];
    }
    __syncthreads();
  }
  int d_ = dt * 32 + drow;
  size_t ob = (size_t)h * 65536 + (size_t)(dpt * 32 + dprow4) * 256 + d_;
  Mt[ob + 0 * 256] = (f16)(acc0 * 0.0625f);
  Mt[ob + 1 * 256] = (f16)(acc1 * 0.0625f);
  Mt[ob + 2 * 256] = (f16)(acc2 * 0.0625f);
  Mt[ob + 3 * 256] = (f16)(acc3 * 0.0625f);
}

// ---------------- P3: Wvt[h][k'][d] = Wv_eff[d][k'] / NUM_HEADS (fp16)
__global__ void prep_v(const float* __restrict__ Wv, f16* __restrict__ Wvt) {
  __shared__ float Ts[16][16];
  __shared__ float Us[16][16];
  int h = blockIdx.x >> 8;
  int kp = blockIdx.x & 255;
  int tid = threadIdx.x;
  Ts[tid >> 4][tid & 15] = T_val(tid >> 4, tid & 15);
  Us[tid >> 4][tid & 15] = U_val(tid >> 4, tid & 15);
  __syncthreads();
  int d = tid;
  int g = d >> 4, i = d & 15;
  int gp = kp >> 4, fp = kp & 15;
  float s = 0.f;
  if (h < 3) {
    s = Wv[(size_t)h * 65536 + (size_t)d * 256 + kp];
  } else {
    for (int ip = 0; ip < 16; ++ip) {
      float tv = Ts[ip][i];
      if (tv != 0.f) {
        float inner = 0.f;
        for (int jj = 0; jj < 16; ++jj) {
          float uv = Us[fp][jj];
          if (uv != 0.f)
            inner += uv * Wv[(size_t)h * 65536 + (size_t)(g * 16 + ip) * 256 + gp * 16 + jj];
        }
        s += tv * inner;
      }
    }
  }
  Wvt[(size_t)h * 65536 + (size_t)kp * 256 + d] = (f16)(s * 0.125f);
}

// ---------------- P4: repack to 16x16x32 fragment-major (coalesced 1KB loads)
__global__ void repack16(const f16* __restrict__ Mt, const f16* __restrict__ Wvt,
                         f16* __restrict__ MtF, f16* __restrict__ WvF) {
  int bid = blockIdx.x;              // 2048 = 2 * 8h * 16t * 8kt
  int which = bid >> 10;
  int h = (bid >> 7) & 7;
  int t16 = (bid >> 3) & 15;
  int kt = bid & 7;
  int l = threadIdx.x;               // 64
  const f16* src = which ? Wvt : Mt;
  f16* dst = which ? WvF : MtF;
  size_t sb = (size_t)h * 65536 + (size_t)(t16 * 16 + (l & 15)) * 256 + kt * 32 + (l >> 4) * 8;
  size_t db = ((size_t)((h * 16 + t16) * 8 + kt) * 64 + l) * 8;
  *(f16x8*)(dst + db) = *(const f16x8*)(src + sb);
}

// ---------------- Main fused kernel ----------------
// 512 thr (8 waves), 2 batches/block, grid 2048, LDS 72192 B -> 2 blocks/CU:
//   Xs [64 rows][XST=264] f16 (+8 pad, bank-staggered rows)   33792 B
//   Y  [64 s][XST] f16                                        33792 B
//   Aat [2b][32 s][36] f16 (stride 36 = 18 banks)              4608 B
// Wave splits (w = tid>>6, 0..7) -- weights loaded ONCE per block:
//   P1a Y:  w = d'-slice of 32 (2 a-tiles), covers all 64 s-rows (4 n-tiles)
//   P1b V:  w = k'-slice of 32 (2 n-tiles), covers all 4 row-tiles (tau)
//   P2:     bq = w>>2 (batch), mt = (w>>1)&1 (s-half), rh = w&1 (softmax r-half)
//   P3/store: w = k'-slice, both batches
__global__ __launch_bounds__(512, 4) void mha_main(
    const float* __restrict__ xg_all,
    const f16* __restrict__ MtF,
    const f16* __restrict__ WvF,
    float* __restrict__ outG)
{
  extern __shared__ char smem[];
  f16* Xs  = (f16*)smem;
  f16* Y   = (f16*)(smem + 33792);
  f16* Aat = (f16*)(smem + 67584);

  const int tid = threadIdx.x;
  const int w   = tid >> 6;
  const int l   = tid & 63;
  const int l15 = l & 15;
  const int l4  = l >> 4;

  // ---- stage x (2 batches, fp32 -> fp16) ----
  const float* xg = xg_all + (size_t)blockIdx.x * 16384;
  #pragma unroll 4
  for (int i = 0; i < 8; ++i) {
    int f4 = i * 512 + tid;
    int row = f4 >> 6;
    int col = (f4 & 63) << 2;
    f32x4 v = *(const f32x4*)(xg + (size_t)f4 * 4);
    f16x4 hv;
    hv[0] = (f16)v[0]; hv[1] = (f16)v[1]; hv[2] = (f16)v[2]; hv[3] = (f16)v[3];
    *(f16x4*)(Xs + row * XST + col) = hv;
  }
  __syncthreads();

  const int bq = w >> 2, mt = (w >> 1) & 1, rh = w & 1;  // P2 split

  // persistent O accumulators: [batch][s-tile][k'-tile] for wave's k'-slice w
  f32x4 O[2][2][2];
  #pragma unroll
  for (int b = 0; b < 2; ++b)
    #pragma unroll
    for (int sm = 0; sm < 2; ++sm)
      #pragma unroll
      for (int n = 0; n < 2; ++n)
        O[b][sm][n] = (f32x4){0.f, 0.f, 0.f, 0.f};

  for (int h = 0; h < 8; ++h) {
    // ================= P1a: Y = Mt . x^T (d'-slice w, all s) =================
    {
      f32x4 C[2][4];
      #pragma unroll
      for (int a = 0; a < 2; ++a)
        #pragma unroll
        for (int n = 0; n < 4; ++n) C[a][n] = (f32x4){0.f, 0.f, 0.f, 0.f};
      #pragma unroll 2
      for (int kt = 0; kt < 8; ++kt) {
        f16x8 A[2], B[4];
        #pragma unroll
        for (int a = 0; a < 2; ++a)
          A[a] = *(const f16x8*)(MtF + ((size_t)((h * 16 + w * 2 + a) * 8 + kt) * 64 + l) * 8);
        #pragma unroll
        for (int n = 0; n < 4; ++n) {
          int srow = n * 16 + l15;
          B[n] = *(const f16x8*)(Xs + srow * XST + kt * 32 + l4 * 8);
        }
        __builtin_amdgcn_s_setprio(1);
        #pragma unroll
        for (int a = 0; a < 2; ++a)
          #pragma unroll
          for (int n = 0; n < 4; ++n)
            C[a][n] = MFMA_F16(A[a], B[n], C[a][n]);
        __builtin_amdgcn_s_setprio(0);
      }
      #pragma unroll
      for (int a = 0; a < 2; ++a)
        #pragma unroll
        for (int n = 0; n < 4; ++n) {
          int srow = n * 16 + l15;
          int dcol = (w * 2 + a) * 16 + l4 * 4;
          f16x4 hv;
          hv[0] = (f16)C[a][n][0]; hv[1] = (f16)C[a][n][1];
          hv[2] = (f16)C[a][n][2]; hv[3] = (f16)C[a][n][3];
          *(f16x4*)(Y + srow * XST + dcol) = hv;
        }
    }
    // ================= P1b: V = x . Wv (k'-slice w, all rows) -> regs =========
    u32 Vh[4][2][2];
    {
      f32x4 VC[4][2];
      #pragma unroll
      for (int tau = 0; tau < 4; ++tau)
        #pragma unroll
        for (int n = 0; n < 2; ++n) VC[tau][n] = (f32x4){0.f, 0.f, 0.f, 0.f};
      #pragma unroll 2
      for (int kt = 0; kt < 8; ++kt) {
        f16x8 Bw[2], Ax[4];
        #pragma unroll
        for (int n = 0; n < 2; ++n)
          Bw[n] = *(const f16x8*)(WvF + ((size_t)((h * 16 + w * 2 + n) * 8 + kt) * 64 + l) * 8);
        #pragma unroll
        for (int tau = 0; tau < 4; ++tau) {
          int xrow = tau * 16 + l15;
          Ax[tau] = *(const f16x8*)(Xs + xrow * XST + kt * 32 + l4 * 8);
        }
        __builtin_amdgcn_s_setprio(1);
        #pragma unroll
        for (int tau = 0; tau < 4; ++tau)
          #pragma unroll
          for (int n = 0; n < 2; ++n)
            VC[tau][n] = MFMA_F16(Ax[tau], Bw[n], VC[tau][n]);
        __builtin_amdgcn_s_setprio(0);
      }
      #pragma unroll
      for (int tau = 0; tau < 4; ++tau)
        #pragma unroll
        for (int n = 0; n < 2; ++n) {
          Vh[tau][n][0] = pkf16(VC[tau][n][0], VC[tau][n][1]);
          Vh[tau][n][1] = pkf16(VC[tau][n][2], VC[tau][n][3]);
        }
    }
    __syncthreads();   // BAR1: Y visible

    // ================= P2: scores + parity softmax =================
    // rh partners duplicate the score MFMAs, split the softmax r-loop.
    {
      f32x4 S0 = (f32x4){0.f, 0.f, 0.f, 0.f};
      f32x4 S1 = (f32x4){0.f, 0.f, 0.f, 0.f};
      int yrow = bq * 32 + mt * 16 + l15;
      int x0 = bq * 32 + l15;
      int x1 = bq * 32 + 16 + l15;
      #pragma unroll
      for (int kt = 0; kt < 8; ++kt) {
        int ks = kt * 32 + l4 * 8;
        f16x8 ay = *(const f16x8*)(Y + yrow * XST + ks);
        f16x8 b0 = *(const f16x8*)(Xs + x0 * XST + ks);
        f16x8 b1 = *(const f16x8*)(Xs + x1 * XST + ks);
        S0 = MFMA_F16(ay, b0, S0);
        S1 = MFMA_F16(ay, b1, S1);
      }
      #pragma unroll
      for (int rr = 0; rr < 2; ++rr) {
        int r = rh * 2 + rr;
        bool valid = ((l & 1) == (r & 1));      // t parity == s parity
        float v0 = valid ? S0[r] : -1e30f;
        float v1 = valid ? S1[r] : -1e30f;
        float mx = fmaxf(v0, v1);
        mx = fmaxf(mx, __shfl_xor(mx, 1));
        mx = fmaxf(mx, __shfl_xor(mx, 2));
        mx = fmaxf(mx, __shfl_xor(mx, 4));
        mx = fmaxf(mx, __shfl_xor(mx, 8));
        float e0 = valid ? __expf(v0 - mx) : 0.f;
        float e1 = valid ? __expf(v1 - mx) : 0.f;
        float sm = e0 + e1;
        sm += __shfl_xor(sm, 1);
        sm += __shfl_xor(sm, 2);
        sm += __shfl_xor(sm, 4);
        sm += __shfl_xor(sm, 8);
        float inv = 1.f / sm;
        int s = mt * 16 + l4 * 4 + r;
        Aat[(bq * 32 + s) * 36 + l15] = (f16)(e0 * inv);
        Aat[(bq * 32 + s) * 36 + 16 + l15] = (f16)(e1 * inv);
      }
    }
    __syncthreads();   // BAR2: Aat visible, all Y reads done

    // ================= P3: O += A . V  (all in registers) =================
    #pragma unroll
    for (int b = 0; b < 2; ++b) {
      #pragma unroll
      for (int sm = 0; sm < 2; ++sm) {
        int arow = (b * 32 + sm * 16 + l15) * 36 + l4 * 4;
        f16x8 bf = comb(*(const f16x4*)(Aat + arow),
                        *(const f16x4*)(Aat + arow + 16));
        #pragma unroll
        for (int n = 0; n < 2; ++n) {
          F8U4 av;
          av.d[0] = Vh[b * 2 + 0][n][0];
          av.d[1] = Vh[b * 2 + 0][n][1];
          av.d[2] = Vh[b * 2 + 1][n][0];
          av.d[3] = Vh[b * 2 + 1][n][1];
          O[b][sm][n] = MFMA_F16(av.v, bf, O[b][sm][n]);
        }
      }
    }
    // no barrier: next P1a writes Y only after BAR2 of this head; Aat(h+1)
    // written only after next BAR1.
  }

  // ---- store O: out[b][s][k'], lane=s, regs=k' quad ----
  #pragma unroll
  for (int b = 0; b < 2; ++b) {
    float* ob = outG + ((size_t)blockIdx.x * 2 + b) * 8192;
    #pragma unroll
    for (int sm = 0; sm < 2; ++sm) {
      int s = sm * 16 + l15;
      #pragma unroll
      for (int n = 0; n < 2; ++n) {
        int kp = w * 32 + n * 16 + l4 * 4;
        *(f32x4*)(ob + s * 256 + kp) = O[b][sm][n];
      }
    }
  }
}

// ---------------- launch ----------------
extern "C" void kernel_launch(void* const* d_in, const int* in_sizes, int n_in,
                              void* d_out, int out_size, void* d_ws, size_t ws_size,
                              hipStream_t stream) {
  const float* x  = (const float*)d_in[0];
  const float* Wq = (const float*)d_in[1];
  const float* Wk = (const float*)d_in[2];
  const float* Wv = (const float*)d_in[3];
  float* out = (float*)d_out;
  char* ws = (char*)d_ws;
  float* WqE = (float*)ws;                       // 2 MB (dead after prep_m)
  float* WkE = (float*)(ws + 2097152);           // 2 MB (dead after prep_m)
  f16*   Mt  = (f16*)(ws + 4194304);             // 1 MB fp16
  f16*   Wvt = (f16*)(ws + 5242880);             // 1 MB fp16
  f16*   MtF = (f16*)ws;                         // 1 MB, overlays WqE
  f16*   WvF = (f16*)(ws + 2097152);             // 1 MB, overlays WkE

  prep_qk<<<4096, 256, 0, stream>>>(Wq, Wk, WqE, WkE);
  prep_m<<<512, 256, 0, stream>>>(WqE, WkE, Mt);
  prep_v<<<2048, 256, 0, stream>>>(Wv, Wvt);
  repack16<<<2048, 64, 0, stream>>>(Mt, Wvt, MtF, WvF);
  mha_main<<<2048, 512, 72192, stream>>>(x, MtF, WvF, out);
}